// Round 1
// baseline (44.563 us; speedup 1.0000x reference)
//
#include <hip/hip_runtime.h>

// ScaledNeuron: IF neuron with soft reset, V_TH=1.0, SCALE=1.0.
// Input  xs: [B=16,C=64,H=64,W=64,T=8] f32, T contiguous.
// Output spikes: same shape/dtype.
// Per neuron: v=0.5; for t: v+=x[t]; s=(v>=1); v-=s; out[t]=s.
// Memory-bound: 128 MiB in + 128 MiB out -> ~43 us at 6.3 TB/s.

__global__ __launch_bounds__(256) void ScaledNeuron_kernel(
    const float* __restrict__ x, float* __restrict__ out, long long n_neurons) {
    long long stride = (long long)gridDim.x * blockDim.x;
    for (long long i = (long long)blockIdx.x * blockDim.x + threadIdx.x;
         i < n_neurons; i += stride) {
        const float4* xp = reinterpret_cast<const float4*>(x + i * 8);
        float4 a = xp[0];
        float4 b = xp[1];
        float r[8] = {a.x, a.y, a.z, a.w, b.x, b.y, b.z, b.w};
        float v = 0.5f;
#pragma unroll
        for (int t = 0; t < 8; ++t) {
            v += r[t];                       // neuronal_charge
            float s = (v >= 1.0f) ? 1.0f : 0.0f;  // fire (v - V_TH >= 0)
            v -= s;                          // soft reset
            r[t] = s;                        // SCALE == 1.0
        }
        float4 o0 = make_float4(r[0], r[1], r[2], r[3]);
        float4 o1 = make_float4(r[4], r[5], r[6], r[7]);
        float4* op = reinterpret_cast<float4*>(out + i * 8);
        op[0] = o0;
        op[1] = o1;
    }
}

extern "C" void kernel_launch(void* const* d_in, const int* in_sizes, int n_in,
                              void* d_out, int out_size, void* d_ws, size_t ws_size,
                              hipStream_t stream) {
    const float* x = (const float*)d_in[0];
    float* out = (float*)d_out;
    long long n_neurons = (long long)in_sizes[0] / 8;  // 4,194,304

    const int block = 256;
    long long want = (n_neurons + block - 1) / block;
    int grid = (int)(want < 2048 ? want : 2048);  // grid-stride, ~8 blocks/CU
    ScaledNeuron_kernel<<<grid, block, 0, stream>>>(x, out, n_neurons);
}